// Round 5
// baseline (197.903 us; speedup 1.0000x reference)
//
#include <hip/hip_runtime.h>

// EMA along T for pos_seq (B=64, T=8192, C=51) fp32.
// y[b,0,c] = x[b,0,c];  y[b,t,c] = 0.25*x[b,t,c] + 0.75*y[b,t-1,c]
//
// R11: bisect of R10's failure + clean test of the concurrency theory.
// R10 changed sizing + multi-wave LDS sharing + XCD swizzle at once and
// failed (absmax 4.07). R11 = EXACT R9 structure (proven passing at 75 us:
// single-wave 64-thread blocks, private LDS, no barriers, xv-register
// transpose, nontemporal stores) with ONLY the sizing changed:
//   TILE 64->32 rows (6528 B LDS), SPAN 256->128, warm-up = 2 tiles
//   (same 64 warm rows as R8/R9 -> same truncation error 0.75^64 ~ 1e-8).
// Grid: 64 b x 64 spans = 4096 single-wave blocks = 16 waves/CU, 2x R9's 8.
// Theory under test (from R9 post-mortem): duration is set by aggregate
// time-averaged outstanding bytes (Little's law), not per-wave critical
// path. 2x wave population -> ~2x outstanding -> BW 2.3 -> ~4 TB/s.
//
//  Per 32-row tile (per wave, fully independent):
//   1. issue 7 masked global_load_dwordx4 (tile k+1) into st[] registers
//   2. LDS -> xv[32] regs (independent ds_reads), register EMA chain,
//      results written back to LDS (WAR on in-order per-wave LDS pipe)
//   3. bulk 16B nontemporal store of tile k (skipped for warm tiles)
//   4. commit st[] -> LDS (compiler's vmcnt wait lands here, with the
//      next tile's 6.5 KB still outstanding)
//  No __syncthreads anywhere; all HBM traffic is dwordx4 (m13 pattern).

typedef float vf4 __attribute__((ext_vector_type(4)));

#define T_DIM 8192
#define C_DIM 51
#define TILE 32
#define SPAN 128
#define NSPAN (T_DIM / SPAN)     // 64 spans per batch row
#define NTILE (SPAN / TILE)      // 4 main tiles
#define WARMT 2                  // 2 warm tiles = 64 rows
#define TILE_F (TILE * C_DIM)    // 1632 floats = 6528 B (16B-aligned: 32*204)
#define TILE_V4 (TILE_F / 4)     // 408
#define VPL 7                    // ceil(408/64); iter 6 has 24 active lanes

__global__ __launch_bounds__(64) void ema_kernel(const float* __restrict__ x,
                                                 float* __restrict__ y) {
    __shared__ float buf[TILE_F];

    const int lane = threadIdx.x;
    const int sp = blockIdx.x % NSPAN;
    const int b = blockIdx.x / NSPAN;
    const size_t plane = (size_t)b * ((size_t)T_DIM * C_DIM);
    const int t0 = sp * SPAN;
    const int wt = (sp != 0) ? WARMT : 0;
    const int ntiles = NTILE + wt;
    const int first_row = t0 - wt * TILE;

    const float* __restrict__ xp = x + plane + (size_t)first_row * C_DIM;
    float* __restrict__ yp = y + plane + (size_t)t0 * C_DIM;

    // ---- prologue: stage tile 0 (regs -> LDS) ----
    vf4 st[VPL];
#pragma unroll
    for (int i = 0; i < VPL; ++i) {
        const int j = i * 64 + lane;
        if (j < TILE_V4) st[i] = *(const vf4*)(xp + 4 * j);
    }
#pragma unroll
    for (int i = 0; i < VPL; ++i) {
        const int j = i * 64 + lane;
        if (j < TILE_V4) *(vf4*)(&buf[4 * j]) = st[i];
    }

    // seed: acc = x[first_row, lane] (span 0: y0 = 0.25*x0+0.75*x0 = x0)
    float acc = 0.0f;
    if (lane < C_DIM) acc = buf[lane];

    for (int k = 0; k < ntiles; ++k) {
        const bool has_next = (k + 1 < ntiles);

        // ---- 1. issue next tile's loads (stay outstanding under scan) ----
        if (has_next) {
            const float* __restrict__ xn = xp + (size_t)(k + 1) * TILE_F;
#pragma unroll
            for (int i = 0; i < VPL; ++i) {
                const int j = i * 64 + lane;
                if (j < TILE_V4) st[i] = *(const vf4*)(xn + 4 * j);
            }
        }

        // ---- 2. transpose to regs, register EMA chain, write back ----
        if (lane < C_DIM) {
            float xv[TILE];
#pragma unroll
            for (int t = 0; t < TILE; ++t)
                xv[t] = buf[t * C_DIM + lane];     // independent ds_reads
#pragma unroll
            for (int t = 0; t < TILE; ++t) {
                acc = fmaf(0.75f, acc, 0.25f * xv[t]);  // pure-reg chain
                buf[t * C_DIM + lane] = acc;            // WAR: no wait needed
            }
        }

        // ---- 3. bulk 16B nontemporal store of computed tile ----
        if (k >= wt) {
            float* __restrict__ yo = yp + (size_t)(k - wt) * TILE_F;
#pragma unroll
            for (int i = 0; i < VPL; ++i) {
                const int j = i * 64 + lane;
                if (j < TILE_V4) {
                    vf4 v = *(const vf4*)(&buf[4 * j]);
                    __builtin_nontemporal_store(v, (vf4*)(yo + 4 * j));
                }
            }
        }

        // ---- 4. commit staged regs (vmcnt wait lands here) ----
        if (has_next) {
#pragma unroll
            for (int i = 0; i < VPL; ++i) {
                const int j = i * 64 + lane;
                if (j < TILE_V4) *(vf4*)(&buf[4 * j]) = st[i];
            }
        }
    }
}

extern "C" void kernel_launch(void* const* d_in, const int* in_sizes, int n_in,
                              void* d_out, int out_size, void* d_ws, size_t ws_size,
                              hipStream_t stream) {
    const float* x = (const float*)d_in[0];
    float* y = (float*)d_out;

    int B = in_sizes[0] / (T_DIM * C_DIM);  // 64
    int grid = B * NSPAN;                   // 4096 single-wave blocks
    ema_kernel<<<grid, 64, 0, stream>>>(x, y);
}

// Round 6
// 193.568 us; speedup vs baseline: 1.0224x; 1.0224x over previous
//
#include <hip/hip_runtime.h>

// EMA along T for pos_seq (B=64, T=8192, C=51) fp32.
// y[b,0,c] = x[b,0,c];  y[b,t,c] = 0.25*x[b,t,c] + 0.75*y[b,t-1,c]
//
// R12: depth-2 load pipeline on the passing R11 structure.
// R11 post-mortem: 2x wave population changed nothing (73 us, 2.55 TB/s,
// occupancy stuck ~18%); R6 hit the same BW at 37% occupancy -> BW is
// insensitive to occupancy AND to per-wave compute (R9). Remaining invariant:
// depth-1 pipeline -> every tile boundary drains the wave's vmcnt queue
// (commit waits ALL that tile's loads; next burst only issues after), so
// time-averaged outstanding bytes are a sliver of the 7 KB peak.
// R12 = two staging sets stA/stB, x2-unrolled loop, loads for tile k+2
// issued BEFORE the commit that waits tile k+1 -> the compiler's counted
// vmcnt(N) keeps ~7-14 entries in flight continuously. ntiles is 4 or 6
// (even), so no tail. Everything else byte-identical to R11.
//
//  Per pair of 32-row tiles (per wave, fully independent, no barriers):
//   even: issue loads(k+2)->stA | scan tile k in LDS | store k | commit stB
//   odd : issue loads(k+3)->stB | scan tile k+1      | store k+1 | commit stA
//  Warm-up: 2 un-stored tiles (64 rows, 0.75^64 ~ 1e-8); span 0 seeds
//  acc = x[0] so y[0] = x[0] (1 ulp). All HBM traffic dwordx4.
//  Grid: 64 b x 64 spans = 4096 single-wave blocks.

typedef float vf4 __attribute__((ext_vector_type(4)));

#define T_DIM 8192
#define C_DIM 51
#define TILE 32
#define SPAN 128
#define NSPAN (T_DIM / SPAN)     // 64 spans per batch row
#define NTILE (SPAN / TILE)      // 4 main tiles
#define WARMT 2                  // 2 warm tiles = 64 rows
#define TILE_F (TILE * C_DIM)    // 1632 floats = 6528 B (16B-aligned: 32*204)
#define TILE_V4 (TILE_F / 4)     // 408
#define VPL 7                    // ceil(408/64); iter 6 has 24 active lanes

__device__ __forceinline__ void load_tile(const float* __restrict__ p,
                                          int lane, vf4 st[VPL]) {
#pragma unroll
    for (int i = 0; i < VPL; ++i) {
        const int j = i * 64 + lane;
        if (j < TILE_V4) st[i] = *(const vf4*)(p + 4 * j);
    }
}

__device__ __forceinline__ void commit_tile(float* __restrict__ buf,
                                            int lane, const vf4 st[VPL]) {
#pragma unroll
    for (int i = 0; i < VPL; ++i) {
        const int j = i * 64 + lane;
        if (j < TILE_V4) *(vf4*)(&buf[4 * j]) = st[i];
    }
}

// scan 32 rows in place in LDS (lane = channel), then 16B nontemporal store
__device__ __forceinline__ void scan_store(float* __restrict__ buf, int lane,
                                           float& acc, bool stored,
                                           float* __restrict__ yo) {
    if (lane < C_DIM) {
        float xv[TILE];
#pragma unroll
        for (int t = 0; t < TILE; ++t)
            xv[t] = buf[t * C_DIM + lane];          // independent ds_reads
#pragma unroll
        for (int t = 0; t < TILE; ++t) {
            acc = fmaf(0.75f, acc, 0.25f * xv[t]);  // pure-reg chain
            buf[t * C_DIM + lane] = acc;            // WAR: in-order LDS pipe
        }
    }
    if (stored) {
#pragma unroll
        for (int i = 0; i < VPL; ++i) {
            const int j = i * 64 + lane;
            if (j < TILE_V4) {
                vf4 v = *(const vf4*)(&buf[4 * j]);
                __builtin_nontemporal_store(v, (vf4*)(yo + 4 * j));
            }
        }
    }
}

__global__ __launch_bounds__(64) void ema_kernel(const float* __restrict__ x,
                                                 float* __restrict__ y) {
    __shared__ float buf[TILE_F];

    const int lane = threadIdx.x;
    const int sp = blockIdx.x % NSPAN;
    const int b = blockIdx.x / NSPAN;
    const size_t plane = (size_t)b * ((size_t)T_DIM * C_DIM);
    const int t0 = sp * SPAN;
    const int wt = (sp != 0) ? WARMT : 0;
    const int ntiles = NTILE + wt;                 // 4 or 6 (even)
    const int first_row = t0 - wt * TILE;

    const float* __restrict__ xp = x + plane + (size_t)first_row * C_DIM;
    float* __restrict__ yp = y + plane + (size_t)t0 * C_DIM;

    // ---- prologue: A <- tile0, B <- tile1 (ntiles >= 4 always), commit A ----
    vf4 stA[VPL], stB[VPL];
    load_tile(xp, lane, stA);
    load_tile(xp + TILE_F, lane, stB);
    commit_tile(buf, lane, stA);

    // seed: acc = x[first_row, lane] (span 0: y0 = 0.25*x0+0.75*x0 = x0)
    float acc = 0.0f;
    if (lane < C_DIM) acc = buf[lane];

    for (int k = 0; k < ntiles; k += 2) {
        // ---- even step: LDS holds tile k; stB holds tile k+1 ----
        if (k + 2 < ntiles)
            load_tile(xp + (size_t)(k + 2) * TILE_F, lane, stA);
        scan_store(buf, lane, acc, k >= wt,
                   yp + (ptrdiff_t)(k - wt) * TILE_F);
        commit_tile(buf, lane, stB);               // waits only B's loads

        // ---- odd step: LDS holds tile k+1; stA holds tile k+2 ----
        if (k + 3 < ntiles)
            load_tile(xp + (size_t)(k + 3) * TILE_F, lane, stB);
        scan_store(buf, lane, acc, k + 1 >= wt,
                   yp + (ptrdiff_t)(k + 1 - wt) * TILE_F);
        if (k + 2 < ntiles)
            commit_tile(buf, lane, stA);           // waits only A's loads
    }
}

extern "C" void kernel_launch(void* const* d_in, const int* in_sizes, int n_in,
                              void* d_out, int out_size, void* d_ws, size_t ws_size,
                              hipStream_t stream) {
    const float* x = (const float*)d_in[0];
    float* y = (float*)d_out;

    int B = in_sizes[0] / (T_DIM * C_DIM);  // 64
    int grid = B * NSPAN;                   // 4096 single-wave blocks
    ema_kernel<<<grid, 64, 0, stream>>>(x, y);
}